// Round 10
// baseline (121.879 us; speedup 1.0000x reference)
//
#include <hip/hip_runtime.h>

#define NN 8192
#define DD 128
#define KSPLIT 16
#define KCHUNK (NN / KSPLIT)      // 512 k per WG
#define BK 32
#define NT (KCHUNK / BK)          // 16 tiles per WG
#define NTILES (NN / BK)          // 256 tiles total
#define TILE_B 16384              // K fp16 8K | Vp fp16 8K
#define OFF_V 8192
#define WAVES 4
#define BQ (WAVES * 32)           // 128 q per WG

// ws layout
#define WS_M   ((size_t)NTILES * TILE_B)                 // 4 MB kst
#define WS_L   (WS_M + (size_t)KSPLIT * NN * 4)
#define WS_OP  (WS_L + (size_t)KSPLIT * NN * 4)
#define WS_NEED (WS_OP + (size_t)KSPLIT * NN * DD * 2)   // ~38.8 MB

typedef __attribute__((ext_vector_type(8))) _Float16 f16x8;
typedef __attribute__((ext_vector_type(2))) _Float16 f16x2;
typedef __attribute__((ext_vector_type(2))) __fp16 fp16v2;
typedef __attribute__((ext_vector_type(8))) short bf16x8;
typedef __attribute__((ext_vector_type(4))) float f32x4;
typedef __attribute__((ext_vector_type(2))) float f32x2;
typedef __attribute__((ext_vector_type(16))) float f32x16;

static __device__ __forceinline__ unsigned short f2bf(float f) {
    union { float f; unsigned u; } v; v.f = f;
    return (unsigned short)((v.u + 0x7FFFu + ((v.u >> 16) & 1u)) >> 16);
}
static __device__ __forceinline__ float bf2f(unsigned short h) {
    union { unsigned u; float f; } v; v.u = ((unsigned)h) << 16;
    return v.f;
}
static __device__ __forceinline__ void gld_lds16(const char* g, char* l) {
    __builtin_amdgcn_global_load_lds(
        (const __attribute__((address_space(1))) unsigned*)g,
        (__attribute__((address_space(3))) unsigned*)l,
        16, 0, 0);
}

// ---------------- prep: build swizzled fp16 tile images ----------------
__global__ __launch_bounds__(256) void attn_prep(
    const float* __restrict__ Km, const float* __restrict__ Vm,
    char* __restrict__ kst)
{
    __shared__ __align__(16) char img[TILE_B];
    const int tt = blockIdx.x;
    const int tid = threadIdx.x;
    const int k0 = tt * BK;
    // K: logical [k][d] fp16, row 256B, swizzle ^((k&15)<<4)  (16-slot XOR)
    #pragma unroll
    for (int i = 0; i < 16; ++i) {
        int idx = i * 256 + tid;
        int d = idx >> 5, k = idx & 31;
        float kv = Km[(size_t)d * NN + k0 + k];
        int b = (k * 256 + d * 2) ^ ((k & 15) << 4);
        *(_Float16*)(img + b) = (_Float16)kv;
    }
    // V: logical [d][j] fp16, row 64B, swizzle ^((d&15)<<4)  (16-slot XOR)
    // j = s2*16 + h*8 + jj  maps actual k = (jj&3) + 4h + 8*(jj>>2) + 16*s2
    #pragma unroll
    for (int i = 0; i < 16; ++i) {
        int idx = i * 256 + tid;
        int d = idx >> 5, j = idx & 31;
        int kl = (j & 3) + 4 * ((j >> 3) & 1) + 8 * ((j >> 2) & 1) + 16 * (j >> 4);
        float vv = Vm[(size_t)d * NN + k0 + kl];
        int b = (d * 64 + j * 2) ^ ((d & 15) << 4);
        *(_Float16*)(img + OFF_V + b) = (_Float16)vv;
    }
    __syncthreads();
    float4* dst = (float4*)(kst + (size_t)tt * TILE_B);
    const float4* src = (const float4*)img;
    #pragma unroll
    for (int i = 0; i < 4; ++i) dst[i * 256 + tid] = src[i * 256 + tid];
}

// ---------------- main: flash attention, fp16 32x32 MFMA, 4 WG/CU ----------------
__global__ __launch_bounds__(256, 4) void attn_main(
    const float* __restrict__ Qm, const char* __restrict__ kst,
    float* __restrict__ mArr, float* __restrict__ lArr,
    _Float16* __restrict__ opart)
{
    __shared__ __align__(16) char smem[2 * TILE_B];   // 32KB double buffer
    const int tid = threadIdx.x;
    const int wave = tid >> 6, lane = tid & 63;
    const int q31 = lane & 31;
    const int h = lane >> 5;
    const int swz = (q31 & 15) << 4;   // shared by K and V reads
    const int ks = blockIdx.x & (KSPLIT - 1);
    const int qb = blockIdx.x >> 4;
    const int q0w = qb * BQ + wave * 32;
    const int qg = q0w + q31;
    const float LOG2E = 1.44269504088896340736f;

    // Q fragments: elem jj of qh[ds] = fp16(Q[16ds+8h+jj][qg]*log2e)
    f16x8 qh[8];
    #pragma unroll
    for (int ds = 0; ds < 8; ++ds)
        #pragma unroll
        for (int jj = 0; jj < 8; ++jj) {
            int d = 16 * ds + 8 * h + jj;
            qh[ds][jj] = (_Float16)(Qm[(size_t)d * NN + qg] * LOG2E);
        }

    f32x16 acc[4];
    #pragma unroll
    for (int dt = 0; dt < 4; ++dt)
        #pragma unroll
        for (int r = 0; r < 16; ++r) acc[dt][r] = 0.f;
    float mrun = -INFINITY, lrun = 0.f;

    const char* kwg = kst + (size_t)(ks * NT) * TILE_B + tid * 16;

    // stage tile 0 -> buf 0
    {
        const char* gs = kwg;
        char* ld = smem + tid * 16;
        #pragma unroll
        for (int i = 0; i < 4; ++i) gld_lds16(gs + i * 4096, ld + i * 4096);
    }
    __syncthreads();

    for (int t = 0; t < NT; ++t) {
        const int cur = t & 1;
        const char* kb = smem + cur * TILE_B;

        if (t + 1 < NT) {   // prefetch next tile into other buffer
            const char* gs = kwg + (size_t)(t + 1) * TILE_B;
            char* ld = smem + (cur ^ 1) * TILE_B + tid * 16;
            #pragma unroll
            for (int i = 0; i < 4; ++i) gld_lds16(gs + i * 4096, ld + i * 4096);
        }

        // ---- QK^T: S^T[k=32][q=32], two independent accumulator chains
        f32x16 Ta, Tb;
        #pragma unroll
        for (int r = 0; r < 16; ++r) { Ta[r] = 0.f; Tb[r] = 0.f; }
        __builtin_amdgcn_s_setprio(1);
        #pragma unroll
        for (int ds = 0; ds < 4; ++ds) {
            int offA = ((q31 << 8) + (2 * ds) * 32 + (h << 4)) ^ swz;
            int offB = ((q31 << 8) + (2 * ds + 1) * 32 + (h << 4)) ^ swz;
            f16x8 ka = *(const f16x8*)(kb + offA);
            f16x8 kb2 = *(const f16x8*)(kb + offB);
            Ta = __builtin_amdgcn_mfma_f32_32x32x16_f16(ka, qh[2 * ds], Ta, 0, 0, 0);
            Tb = __builtin_amdgcn_mfma_f32_32x32x16_f16(kb2, qh[2 * ds + 1], Tb, 0, 0, 0);
        }
        __builtin_amdgcn_s_setprio(0);
        f32x16 T;
        #pragma unroll
        for (int r = 0; r < 16; ++r) T[r] = Ta[r] + Tb[r];

        // ---- online softmax (per-lane q; halves combined via xor32)
        float a0 = fmaxf(fmaxf(T[0], T[1]), T[2]);
        float a1 = fmaxf(fmaxf(T[3], T[4]), T[5]);
        float a2 = fmaxf(fmaxf(T[6], T[7]), T[8]);
        float a3 = fmaxf(fmaxf(T[9], T[10]), T[11]);
        float a4 = fmaxf(fmaxf(T[12], T[13]), T[14]);
        float tmax = fmaxf(fmaxf(fmaxf(a0, a1), a2), fmaxf(fmaxf(a3, a4), T[15]));
        tmax = fmaxf(tmax, __shfl_xor(tmax, 32, 64));

        if (__any(tmax > mrun)) {    // defer-max: exact skip when sc==1 everywhere
            float mnew = fmaxf(mrun, tmax);
            float sc = __builtin_amdgcn_exp2f(mrun - mnew);
            mrun = mnew; lrun *= sc;
            #pragma unroll
            for (int dt = 0; dt < 4; ++dt)
                #pragma unroll
                for (int r = 0; r < 16; ++r) acc[dt][r] *= sc;
        }

        float p[16];
        #pragma unroll
        for (int r = 0; r < 16; ++r)
            p[r] = __builtin_amdgcn_exp2f(T[r] - mrun);
        float s0 = (p[0] + p[1]) + (p[2] + p[3]);
        float s1 = (p[4] + p[5]) + (p[6] + p[7]);
        float s2 = (p[8] + p[9]) + (p[10] + p[11]);
        float s3 = (p[12] + p[13]) + (p[14] + p[15]);
        lrun += (s0 + s1) + (s2 + s3);
        union { f16x8 v[2]; fp16v2 h2[8]; } pu;
        #pragma unroll
        for (int r = 0; r < 8; ++r)
            pu.h2[r] = __builtin_amdgcn_cvt_pkrtz(p[2 * r], p[2 * r + 1]);

        // ---- PV: O^T[d][q] += V^T * P  (k-permuted contraction)
        const char* vb = kb + OFF_V;
        __builtin_amdgcn_s_setprio(1);
        #pragma unroll
        for (int dt = 0; dt < 4; ++dt) {
            int vbase = (dt * 32 + q31) * 64 + (h << 4);
            f16x8 v0 = *(const f16x8*)(vb + ((vbase) ^ swz));
            f16x8 v1 = *(const f16x8*)(vb + ((vbase + 32) ^ swz));
            acc[dt] = __builtin_amdgcn_mfma_f32_32x32x16_f16(v0, pu.v[0], acc[dt], 0, 0, 0);
            acc[dt] = __builtin_amdgcn_mfma_f32_32x32x16_f16(v1, pu.v[1], acc[dt], 0, 0, 0);
        }
        __builtin_amdgcn_s_setprio(0);

        __syncthreads();
    }

    // ---- epilogue: partials to ws
    lrun += __shfl_xor(lrun, 32, 64);
    if (lane < 32) {
        mArr[ks * NN + qg] = mrun;
        lArr[ks * NN + qg] = lrun;
    }
    #pragma unroll
    for (int dt = 0; dt < 4; ++dt)
        #pragma unroll
        for (int r = 0; r < 16; ++r) {
            int d = dt * 32 + (r & 3) + 8 * (r >> 2) + 4 * h;
            opart[((size_t)ks * DD + d) * NN + qg] = (_Float16)acc[dt][r];
        }
}

// ---------------- combine: merge split-k partials ----------------
__global__ __launch_bounds__(256) void attn_combine(
    const _Float16* __restrict__ opart, const float* __restrict__ mArr,
    const float* __restrict__ lArr, float* __restrict__ out)
{
    const int tid = threadIdx.x;
    const int qg = blockIdx.x >> 3;            // groups of 512 q
    const int dseg = (blockIdx.x & 7) * 16;
    const int q = qg * 512 + tid * 2;

    f32x2 mv[KSPLIT];
    float M0 = -INFINITY, M1 = -INFINITY;
    #pragma unroll
    for (int s = 0; s < KSPLIT; ++s) {
        mv[s] = *(const f32x2*)&mArr[(size_t)s * NN + q];
        M0 = fmaxf(M0, mv[s][0]);
        M1 = fmaxf(M1, mv[s][1]);
    }
    float L0 = 0.f, L1 = 0.f;
    f32x2 w[KSPLIT];
    #pragma unroll
    for (int s = 0; s < KSPLIT; ++s) {
        f32x2 lv = *(const f32x2*)&lArr[(size_t)s * NN + q];
        w[s][0] = __builtin_amdgcn_exp2f(mv[s][0] - M0);
        w[s][1] = __builtin_amdgcn_exp2f(mv[s][1] - M1);
        L0 += w[s][0] * lv[0];
        L1 += w[s][1] * lv[1];
    }
    float i0 = 1.f / L0, i1 = 1.f / L1;
    #pragma unroll
    for (int s = 0; s < KSPLIT; ++s) { w[s][0] *= i0; w[s][1] *= i1; }

    for (int dd = 0; dd < 16; ++dd) {
        int d = dseg + dd;
        float a0 = 0.f, a1 = 0.f;
        #pragma unroll
        for (int s = 0; s < KSPLIT; ++s) {
            f16x2 u = *(const f16x2*)&opart[((size_t)s * DD + d) * NN + q];
            a0 += w[s][0] * (float)u[0];
            a1 += w[s][1] * (float)u[1];
        }
        f32x2 o; o[0] = a0; o[1] = a1;
        *(f32x2*)&out[(size_t)d * NN + q] = o;
    }
}

// ---------------- fallback (round-1 kernel, used if ws too small) ----------------
__global__ __launch_bounds__(512, 2) void attn_fwd_fb(
    const float* __restrict__ Qm, const float* __restrict__ Km,
    const float* __restrict__ Vm, float* __restrict__ out)
{
    const int tid  = threadIdx.x;
    const int wave = tid >> 6;
    const int lane = tid & 63;
    const int c = lane & 15;
    const int g = lane >> 4;
    const int q0 = blockIdx.x * 32;
    const float LOG2E = 1.44269504088896340736f;

    bf16x8 qhi[2][4], qlo[2][4];
    #pragma unroll
    for (int qt = 0; qt < 2; ++qt)
        #pragma unroll
        for (int ds = 0; ds < 4; ++ds)
            #pragma unroll
            for (int jj = 0; jj < 8; ++jj) {
                int d = ds * 32 + 8 * g + jj;
                float qv = Qm[(size_t)d * NN + (q0 + qt * 16 + c)] * LOG2E;
                unsigned short hv = f2bf(qv);
                qhi[qt][ds][jj] = (short)hv;
                qlo[qt][ds][jj] = (short)f2bf(qv - bf2f(hv));
            }

    f32x4 acc[2][8];
    #pragma unroll
    for (int a = 0; a < 2; ++a)
        #pragma unroll
        for (int b = 0; b < 8; ++b)
            acc[a][b] = (f32x4){0.f, 0.f, 0.f, 0.f};
    float mrun[2] = {-INFINITY, -INFINITY};
    float lrun[2] = {0.f, 0.f};
    const int kw0 = wave * (NN / 8);

    for (int t = 0; t < (NN / 8) / 64; ++t) {
        const int k0 = kw0 + t * 64;
        f32x4 T[4][2];
        #pragma unroll
        for (int mkt = 0; mkt < 4; ++mkt) {
            T[mkt][0] = (f32x4){0.f, 0.f, 0.f, 0.f};
            T[mkt][1] = (f32x4){0.f, 0.f, 0.f, 0.f};
        }
        #pragma unroll
        for (int mkt = 0; mkt < 4; ++mkt) {
            const int kc = k0 + mkt * 16 + c;
            #pragma unroll
            for (int ds = 0; ds < 4; ++ds) {
                bf16x8 khi, klo;
                #pragma unroll
                for (int jj = 0; jj < 8; ++jj) {
                    int d = ds * 32 + 8 * g + jj;
                    float kv = Km[(size_t)d * NN + kc];
                    unsigned short hv = f2bf(kv);
                    khi[jj] = (short)hv;
                    klo[jj] = (short)f2bf(kv - bf2f(hv));
                }
                #pragma unroll
                for (int qt = 0; qt < 2; ++qt) {
                    T[mkt][qt] = __builtin_amdgcn_mfma_f32_16x16x32_bf16(khi, qhi[qt][ds], T[mkt][qt], 0, 0, 0);
                    T[mkt][qt] = __builtin_amdgcn_mfma_f32_16x16x32_bf16(khi, qlo[qt][ds], T[mkt][qt], 0, 0, 0);
                    T[mkt][qt] = __builtin_amdgcn_mfma_f32_16x16x32_bf16(klo, qhi[qt][ds], T[mkt][qt], 0, 0, 0);
                }
            }
        }
        bf16x8 pfrag[2][2];
        float scl[2];
        #pragma unroll
        for (int qt = 0; qt < 2; ++qt) {
            float tmax = T[0][qt][0];
            #pragma unroll
            for (int mkt = 0; mkt < 4; ++mkt)
                #pragma unroll
                for (int r = 0; r < 4; ++r)
                    tmax = fmaxf(tmax, T[mkt][qt][r]);
            tmax = fmaxf(tmax, __shfl_xor(tmax, 16, 64));
            tmax = fmaxf(tmax, __shfl_xor(tmax, 32, 64));
            float mnew = fmaxf(mrun[qt], tmax);
            float sc = __builtin_amdgcn_exp2f(mrun[qt] - mnew);
            mrun[qt] = mnew;
            lrun[qt] *= sc;
            scl[qt] = sc;
            #pragma unroll
            for (int s = 0; s < 2; ++s)
                #pragma unroll
                for (int hf = 0; hf < 2; ++hf) {
                    int mkt = 2 * s + hf;
                    #pragma unroll
                    for (int r = 0; r < 4; ++r) {
                        float pv = __builtin_amdgcn_exp2f(T[mkt][qt][r] - mnew);
                        unsigned short pb = f2bf(pv);
                        lrun[qt] += bf2f(pb);
                        pfrag[qt][s][hf * 4 + r] = (short)pb;
                    }
                }
        }
        #pragma unroll
        for (int qt = 0; qt < 2; ++qt)
            #pragma unroll
            for (int r = 0; r < 4; ++r) {
                float f = __shfl(scl[qt], 4 * g + r, 64);
                #pragma unroll
                for (int dt = 0; dt < 8; ++dt)
                    acc[qt][dt][r] *= f;
            }
        #pragma unroll
        for (int s = 0; s < 2; ++s)
            #pragma unroll
            for (int dt = 0; dt < 8; ++dt) {
                const float* vp = Vm + (size_t)(dt * 16 + c) * NN + (k0 + 32 * s + 4 * g);
                f32x4 v0 = *(const f32x4*)vp;
                f32x4 v1 = *(const f32x4*)(vp + 16);
                bf16x8 vbf;
                #pragma unroll
                for (int e = 0; e < 4; ++e) {
                    vbf[e]     = (short)f2bf(v0[e]);
                    vbf[4 + e] = (short)f2bf(v1[e]);
                }
                #pragma unroll
                for (int qt = 0; qt < 2; ++qt)
                    acc[qt][dt] = __builtin_amdgcn_mfma_f32_16x16x32_bf16(pfrag[qt][s], vbf, acc[qt][dt], 0, 0, 0);
            }
    }

    __shared__ float obuf[32][DD + 4];
    __shared__ float mbuf[8][32];
    __shared__ float lbuf[8][32];
    __shared__ float lsbuf[32];
    #pragma unroll
    for (int qt = 0; qt < 2; ++qt) {
        lrun[qt] += __shfl_xor(lrun[qt], 16, 64);
        lrun[qt] += __shfl_xor(lrun[qt], 32, 64);
    }
    if (lane < 16) {
        mbuf[wave][c]      = mrun[0];
        mbuf[wave][16 + c] = mrun[1];
        lbuf[wave][c]      = lrun[0];
        lbuf[wave][16 + c] = lrun[1];
    }
    for (int i = tid; i < 32 * (DD + 4); i += 512)
        (&obuf[0][0])[i] = 0.f;
    __syncthreads();
    float fac[2];
    {
        float lst[2];
        #pragma unroll
        for (int qt = 0; qt < 2; ++qt) {
            int q = qt * 16 + c;
            float mm = -INFINITY;
            #pragma unroll
            for (int w = 0; w < 8; ++w) mm = fmaxf(mm, mbuf[w][q]);
            float ls = 0.f;
            #pragma unroll
            for (int w = 0; w < 8; ++w)
                ls += __builtin_amdgcn_exp2f(mbuf[w][q] - mm) * lbuf[w][q];
            fac[qt] = __builtin_amdgcn_exp2f(mrun[qt] - mm);
            lst[qt] = ls;
        }
        if (wave == 0 && lane < 16) {
            lsbuf[c]      = lst[0];
            lsbuf[16 + c] = lst[1];
        }
    }
    float facr[2][4];
    #pragma unroll
    for (int qt = 0; qt < 2; ++qt)
        #pragma unroll
        for (int r = 0; r < 4; ++r)
            facr[qt][r] = __shfl(fac[qt], 4 * g + r, 64);
    for (int w = 0; w < 8; ++w) {
        if (wave == w) {
            #pragma unroll
            for (int qt = 0; qt < 2; ++qt)
                #pragma unroll
                for (int dt = 0; dt < 8; ++dt)
                    #pragma unroll
                    for (int r = 0; r < 4; ++r)
                        obuf[qt * 16 + 4 * g + r][dt * 16 + c] += facr[qt][r] * acc[qt][dt][r];
        }
        __syncthreads();
    }
    const int qq = tid & 31;
    const int dg = tid >> 5;
    const float inv = 1.f / lsbuf[qq];
    #pragma unroll
    for (int i = 0; i < 8; ++i) {
        int d = dg * 8 + i;
        out[(size_t)d * NN + q0 + qq] = obuf[qq][d] * inv;
    }
}

extern "C" void kernel_launch(void* const* d_in, const int* in_sizes, int n_in,
                              void* d_out, int out_size, void* d_ws, size_t ws_size,
                              hipStream_t stream) {
    const float* Q = (const float*)d_in[0];
    const float* K = (const float*)d_in[1];
    const float* V = (const float*)d_in[2];
    float* out = (float*)d_out;

    if (ws_size < WS_NEED || d_ws == nullptr) {
        hipLaunchKernelGGL(attn_fwd_fb, dim3(NN / 32), dim3(512), 0, stream, Q, K, V, out);
        return;
    }
    char* ws = (char*)d_ws;
    char* kst = ws;
    float* mArr = (float*)(ws + WS_M);
    float* lArr = (float*)(ws + WS_L);
    _Float16* opart = (_Float16*)(ws + WS_OP);

    hipLaunchKernelGGL(attn_prep, dim3(NTILES), dim3(256), 0, stream, K, V, kst);
    hipLaunchKernelGGL(attn_main, dim3(KSPLIT * (NN / BQ)), dim3(256), 0, stream, Q, kst, mArr, lArr, opart);
    hipLaunchKernelGGL(attn_combine, dim3((NN / 512) * 8), dim3(256), 0, stream, opart, mArr, lArr, out);
}

// Round 11
// 75.069 us; speedup vs baseline: 1.6236x; 1.6236x over previous
//
#include <hip/hip_runtime.h>

#define NN 8192
#define DD 128
#define KSPLIT 16
#define KCHUNK (NN / KSPLIT)      // 512 k per WG
#define BK 32
#define NT (KCHUNK / BK)          // 16 tiles per WG
#define NTILES (NN / BK)          // 256 tiles total
#define TILE_B 16384              // K fp16 8K | Vp fp16 8K
#define OFF_V 8192
#define WAVES 4
#define BQ (WAVES * 32)           // 128 q per WG

// ws layout
#define WS_M   ((size_t)NTILES * TILE_B)                 // 4 MB kst
#define WS_L   (WS_M + (size_t)KSPLIT * NN * 4)
#define WS_OP  (WS_L + (size_t)KSPLIT * NN * 4)
#define WS_NEED (WS_OP + (size_t)KSPLIT * NN * DD * 2)   // ~38.8 MB

typedef __attribute__((ext_vector_type(8))) _Float16 f16x8;
typedef __attribute__((ext_vector_type(2))) _Float16 f16x2;
typedef __attribute__((ext_vector_type(2))) __fp16 fp16v2;
typedef __attribute__((ext_vector_type(8))) short bf16x8;
typedef __attribute__((ext_vector_type(4))) float f32x4;
typedef __attribute__((ext_vector_type(2))) float f32x2;
typedef __attribute__((ext_vector_type(16))) float f32x16;

static __device__ __forceinline__ unsigned short f2bf(float f) {
    union { float f; unsigned u; } v; v.f = f;
    return (unsigned short)((v.u + 0x7FFFu + ((v.u >> 16) & 1u)) >> 16);
}
static __device__ __forceinline__ float bf2f(unsigned short h) {
    union { unsigned u; float f; } v; v.u = ((unsigned)h) << 16;
    return v.f;
}
static __device__ __forceinline__ void gld_lds16(const char* g, char* l) {
    __builtin_amdgcn_global_load_lds(
        (const __attribute__((address_space(1))) unsigned*)g,
        (__attribute__((address_space(3))) unsigned*)l,
        16, 0, 0);
}

// ---------------- prep: build swizzled fp16 tile images ----------------
__global__ __launch_bounds__(256) void attn_prep(
    const float* __restrict__ Km, const float* __restrict__ Vm,
    char* __restrict__ kst)
{
    __shared__ __align__(16) char img[TILE_B];
    const int tt = blockIdx.x;
    const int tid = threadIdx.x;
    const int k0 = tt * BK;
    // K: logical [k][d] fp16, row 256B, swizzle ^((k&15)<<4)  (16-slot XOR)
    #pragma unroll
    for (int i = 0; i < 16; ++i) {
        int idx = i * 256 + tid;
        int d = idx >> 5, k = idx & 31;
        float kv = Km[(size_t)d * NN + k0 + k];
        int b = (k * 256 + d * 2) ^ ((k & 15) << 4);
        *(_Float16*)(img + b) = (_Float16)kv;
    }
    // V: logical [d][j] fp16, row 64B, swizzle ^((d&15)<<4)  (16-slot XOR)
    // j = s2*16 + h*8 + jj  maps actual k = (jj&3) + 4h + 8*(jj>>2) + 16*s2
    #pragma unroll
    for (int i = 0; i < 16; ++i) {
        int idx = i * 256 + tid;
        int d = idx >> 5, j = idx & 31;
        int kl = (j & 3) + 4 * ((j >> 3) & 1) + 8 * ((j >> 2) & 1) + 16 * (j >> 4);
        float vv = Vm[(size_t)d * NN + k0 + kl];
        int b = (d * 64 + j * 2) ^ ((d & 15) << 4);
        *(_Float16*)(img + OFF_V + b) = (_Float16)vv;
    }
    __syncthreads();
    float4* dst = (float4*)(kst + (size_t)tt * TILE_B);
    const float4* src = (const float4*)img;
    #pragma unroll
    for (int i = 0; i < 4; ++i) dst[i * 256 + tid] = src[i * 256 + tid];
}

// ---------------- main: flash attention, fp16 32x32 MFMA ----------------
__global__ __launch_bounds__(256, 3) void attn_main(
    const float* __restrict__ Qm, const char* __restrict__ kst,
    float* __restrict__ mArr, float* __restrict__ lArr,
    _Float16* __restrict__ opart)
{
    __shared__ __align__(16) char smem[2 * TILE_B];   // 32KB double buffer
    const int tid = threadIdx.x;
    const int wave = tid >> 6, lane = tid & 63;
    const int q31 = lane & 31;
    const int h = lane >> 5;
    const int swz = (q31 & 15) << 4;   // shared by K and V reads
    const int ks = blockIdx.x & (KSPLIT - 1);
    const int qb = blockIdx.x >> 4;
    const int q0w = qb * BQ + wave * 32;
    const int qg = q0w + q31;
    const float LOG2E = 1.44269504088896340736f;

    // Q fragments: elem jj of qh[ds] = fp16(Q[16ds+8h+jj][qg]*log2e)
    f16x8 qh[8];
    #pragma unroll
    for (int ds = 0; ds < 8; ++ds)
        #pragma unroll
        for (int jj = 0; jj < 8; ++jj) {
            int d = 16 * ds + 8 * h + jj;
            qh[ds][jj] = (_Float16)(Qm[(size_t)d * NN + qg] * LOG2E);
        }

    f32x16 acc[4];
    #pragma unroll
    for (int dt = 0; dt < 4; ++dt)
        #pragma unroll
        for (int r = 0; r < 16; ++r) acc[dt][r] = 0.f;
    float mrun = -INFINITY, lrun = 0.f;

    const char* kwg = kst + (size_t)(ks * NT) * TILE_B + tid * 16;

    // stage tile 0 -> buf 0
    {
        const char* gs = kwg;
        char* ld = smem + tid * 16;
        #pragma unroll
        for (int i = 0; i < 4; ++i) gld_lds16(gs + i * 4096, ld + i * 4096);
    }
    __syncthreads();

    for (int t = 0; t < NT; ++t) {
        const int cur = t & 1;
        const char* kb = smem + cur * TILE_B;

        if (t + 1 < NT) {   // prefetch next tile into other buffer
            const char* gs = kwg + (size_t)(t + 1) * TILE_B;
            char* ld = smem + (cur ^ 1) * TILE_B + tid * 16;
            #pragma unroll
            for (int i = 0; i < 4; ++i) gld_lds16(gs + i * 4096, ld + i * 4096);
        }

        // ---- QK^T: S^T[k=32][q=32], single fp16 chain, 8 d-steps of 16
        f32x16 T;
        #pragma unroll
        for (int r = 0; r < 16; ++r) T[r] = 0.f;
        __builtin_amdgcn_s_setprio(1);
        #pragma unroll
        for (int ds = 0; ds < 8; ++ds) {
            int off = ((q31 << 8) + ds * 32 + (h << 4)) ^ swz;
            f16x8 kh = *(const f16x8*)(kb + off);
            T = __builtin_amdgcn_mfma_f32_32x32x16_f16(kh, qh[ds], T, 0, 0, 0);
        }
        __builtin_amdgcn_s_setprio(0);

        // ---- online softmax (per-lane q; halves combined via xor32)
        float a0 = fmaxf(fmaxf(T[0], T[1]), T[2]);
        float a1 = fmaxf(fmaxf(T[3], T[4]), T[5]);
        float a2 = fmaxf(fmaxf(T[6], T[7]), T[8]);
        float a3 = fmaxf(fmaxf(T[9], T[10]), T[11]);
        float a4 = fmaxf(fmaxf(T[12], T[13]), T[14]);
        float tmax = fmaxf(fmaxf(fmaxf(a0, a1), a2), fmaxf(fmaxf(a3, a4), T[15]));
        tmax = fmaxf(tmax, __shfl_xor(tmax, 32, 64));

        if (__any(tmax > mrun)) {    // defer-max: exact skip when sc==1 everywhere
            float mnew = fmaxf(mrun, tmax);
            float sc = __builtin_amdgcn_exp2f(mrun - mnew);
            mrun = mnew; lrun *= sc;
            #pragma unroll
            for (int dt = 0; dt < 4; ++dt)
                #pragma unroll
                for (int r = 0; r < 16; ++r) acc[dt][r] *= sc;
        }

        float p[16];
        #pragma unroll
        for (int r = 0; r < 16; ++r)
            p[r] = __builtin_amdgcn_exp2f(T[r] - mrun);
        float s0 = (p[0] + p[1]) + (p[2] + p[3]);
        float s1 = (p[4] + p[5]) + (p[6] + p[7]);
        float s2 = (p[8] + p[9]) + (p[10] + p[11]);
        float s3 = (p[12] + p[13]) + (p[14] + p[15]);
        lrun += (s0 + s1) + (s2 + s3);
        union { f16x8 v[2]; fp16v2 h2[8]; } pu;
        #pragma unroll
        for (int r = 0; r < 8; ++r)
            pu.h2[r] = __builtin_amdgcn_cvt_pkrtz(p[2 * r], p[2 * r + 1]);

        // ---- PV: O^T[d][q] += V^T * P  (k-permuted contraction)
        const char* vb = kb + OFF_V;
        __builtin_amdgcn_s_setprio(1);
        #pragma unroll
        for (int dt = 0; dt < 4; ++dt) {
            int vbase = (dt * 32 + q31) * 64 + (h << 4);
            f16x8 v0 = *(const f16x8*)(vb + ((vbase) ^ swz));
            f16x8 v1 = *(const f16x8*)(vb + ((vbase + 32) ^ swz));
            acc[dt] = __builtin_amdgcn_mfma_f32_32x32x16_f16(v0, pu.v[0], acc[dt], 0, 0, 0);
            acc[dt] = __builtin_amdgcn_mfma_f32_32x32x16_f16(v1, pu.v[1], acc[dt], 0, 0, 0);
        }
        __builtin_amdgcn_s_setprio(0);

        __syncthreads();
    }

    // ---- epilogue: partials to ws (non-temporal: write-once, no L2 pollution)
    lrun += __shfl_xor(lrun, 32, 64);
    if (lane < 32) {
        __builtin_nontemporal_store(mrun, &mArr[ks * NN + qg]);
        __builtin_nontemporal_store(lrun, &lArr[ks * NN + qg]);
    }
    #pragma unroll
    for (int dt = 0; dt < 4; ++dt)
        #pragma unroll
        for (int r = 0; r < 16; ++r) {
            int d = dt * 32 + (r & 3) + 8 * (r >> 2) + 4 * h;
            __builtin_nontemporal_store((_Float16)acc[dt][r],
                &opart[((size_t)ks * DD + d) * NN + qg]);
        }
}

// ---------------- combine: merge split-k partials ----------------
__global__ __launch_bounds__(256) void attn_combine(
    const _Float16* __restrict__ opart, const float* __restrict__ mArr,
    const float* __restrict__ lArr, float* __restrict__ out)
{
    const int tid = threadIdx.x;
    const int qg = blockIdx.x >> 3;            // groups of 512 q
    const int dseg = (blockIdx.x & 7) * 16;
    const int q = qg * 512 + tid * 2;

    f32x2 mv[KSPLIT];
    float M0 = -INFINITY, M1 = -INFINITY;
    #pragma unroll
    for (int s = 0; s < KSPLIT; ++s) {
        mv[s] = *(const f32x2*)&mArr[(size_t)s * NN + q];
        M0 = fmaxf(M0, mv[s][0]);
        M1 = fmaxf(M1, mv[s][1]);
    }
    float L0 = 0.f, L1 = 0.f;
    f32x2 w[KSPLIT];
    #pragma unroll
    for (int s = 0; s < KSPLIT; ++s) {
        f32x2 lv = *(const f32x2*)&lArr[(size_t)s * NN + q];
        w[s][0] = __builtin_amdgcn_exp2f(mv[s][0] - M0);
        w[s][1] = __builtin_amdgcn_exp2f(mv[s][1] - M1);
        L0 += w[s][0] * lv[0];
        L1 += w[s][1] * lv[1];
    }
    float i0 = 1.f / L0, i1 = 1.f / L1;
    #pragma unroll
    for (int s = 0; s < KSPLIT; ++s) { w[s][0] *= i0; w[s][1] *= i1; }

    for (int dd = 0; dd < 16; ++dd) {
        int d = dseg + dd;
        float a0 = 0.f, a1 = 0.f;
        #pragma unroll
        for (int s = 0; s < KSPLIT; ++s) {
            f16x2 u = __builtin_nontemporal_load(
                (const f16x2*)&opart[((size_t)s * DD + d) * NN + q]);
            a0 += w[s][0] * (float)u[0];
            a1 += w[s][1] * (float)u[1];
        }
        f32x2 o; o[0] = a0; o[1] = a1;
        *(f32x2*)&out[(size_t)d * NN + q] = o;
    }
}

// ---------------- fallback (round-1 kernel, used if ws too small) ----------------
__global__ __launch_bounds__(512, 2) void attn_fwd_fb(
    const float* __restrict__ Qm, const float* __restrict__ Km,
    const float* __restrict__ Vm, float* __restrict__ out)
{
    const int tid  = threadIdx.x;
    const int wave = tid >> 6;
    const int lane = tid & 63;
    const int c = lane & 15;
    const int g = lane >> 4;
    const int q0 = blockIdx.x * 32;
    const float LOG2E = 1.44269504088896340736f;

    bf16x8 qhi[2][4], qlo[2][4];
    #pragma unroll
    for (int qt = 0; qt < 2; ++qt)
        #pragma unroll
        for (int ds = 0; ds < 4; ++ds)
            #pragma unroll
            for (int jj = 0; jj < 8; ++jj) {
                int d = ds * 32 + 8 * g + jj;
                float qv = Qm[(size_t)d * NN + (q0 + qt * 16 + c)] * LOG2E;
                unsigned short hv = f2bf(qv);
                qhi[qt][ds][jj] = (short)hv;
                qlo[qt][ds][jj] = (short)f2bf(qv - bf2f(hv));
            }

    f32x4 acc[2][8];
    #pragma unroll
    for (int a = 0; a < 2; ++a)
        #pragma unroll
        for (int b = 0; b < 8; ++b)
            acc[a][b] = (f32x4){0.f, 0.f, 0.f, 0.f};
    float mrun[2] = {-INFINITY, -INFINITY};
    float lrun[2] = {0.f, 0.f};
    const int kw0 = wave * (NN / 8);

    for (int t = 0; t < (NN / 8) / 64; ++t) {
        const int k0 = kw0 + t * 64;
        f32x4 T[4][2];
        #pragma unroll
        for (int mkt = 0; mkt < 4; ++mkt) {
            T[mkt][0] = (f32x4){0.f, 0.f, 0.f, 0.f};
            T[mkt][1] = (f32x4){0.f, 0.f, 0.f, 0.f};
        }
        #pragma unroll
        for (int mkt = 0; mkt < 4; ++mkt) {
            const int kc = k0 + mkt * 16 + c;
            #pragma unroll
            for (int ds = 0; ds < 4; ++ds) {
                bf16x8 khi, klo;
                #pragma unroll
                for (int jj = 0; jj < 8; ++jj) {
                    int d = ds * 32 + 8 * g + jj;
                    float kv = Km[(size_t)d * NN + kc];
                    unsigned short hv = f2bf(kv);
                    khi[jj] = (short)hv;
                    klo[jj] = (short)f2bf(kv - bf2f(hv));
                }
                #pragma unroll
                for (int qt = 0; qt < 2; ++qt) {
                    T[mkt][qt] = __builtin_amdgcn_mfma_f32_16x16x32_bf16(khi, qhi[qt][ds], T[mkt][qt], 0, 0, 0);
                    T[mkt][qt] = __builtin_amdgcn_mfma_f32_16x16x32_bf16(khi, qlo[qt][ds], T[mkt][qt], 0, 0, 0);
                    T[mkt][qt] = __builtin_amdgcn_mfma_f32_16x16x32_bf16(klo, qhi[qt][ds], T[mkt][qt], 0, 0, 0);
                }
            }
        }
        bf16x8 pfrag[2][2];
        float scl[2];
        #pragma unroll
        for (int qt = 0; qt < 2; ++qt) {
            float tmax = T[0][qt][0];
            #pragma unroll
            for (int mkt = 0; mkt < 4; ++mkt)
                #pragma unroll
                for (int r = 0; r < 4; ++r)
                    tmax = fmaxf(tmax, T[mkt][qt][r]);
            tmax = fmaxf(tmax, __shfl_xor(tmax, 16, 64));
            tmax = fmaxf(tmax, __shfl_xor(tmax, 32, 64));
            float mnew = fmaxf(mrun[qt], tmax);
            float sc = __builtin_amdgcn_exp2f(mrun[qt] - mnew);
            mrun[qt] = mnew;
            lrun[qt] *= sc;
            scl[qt] = sc;
            #pragma unroll
            for (int s = 0; s < 2; ++s)
                #pragma unroll
                for (int hf = 0; hf < 2; ++hf) {
                    int mkt = 2 * s + hf;
                    #pragma unroll
                    for (int r = 0; r < 4; ++r) {
                        float pv = __builtin_amdgcn_exp2f(T[mkt][qt][r] - mnew);
                        unsigned short pb = f2bf(pv);
                        lrun[qt] += bf2f(pb);
                        pfrag[qt][s][hf * 4 + r] = (short)pb;
                    }
                }
        }
        #pragma unroll
        for (int qt = 0; qt < 2; ++qt)
            #pragma unroll
            for (int r = 0; r < 4; ++r) {
                float f = __shfl(scl[qt], 4 * g + r, 64);
                #pragma unroll
                for (int dt = 0; dt < 8; ++dt)
                    acc[qt][dt][r] *= f;
            }
        #pragma unroll
        for (int s = 0; s < 2; ++s)
            #pragma unroll
            for (int dt = 0; dt < 8; ++dt) {
                const float* vp = Vm + (size_t)(dt * 16 + c) * NN + (k0 + 32 * s + 4 * g);
                f32x4 v0 = *(const f32x4*)vp;
                f32x4 v1 = *(const f32x4*)(vp + 16);
                bf16x8 vbf;
                #pragma unroll
                for (int e = 0; e < 4; ++e) {
                    vbf[e]     = (short)f2bf(v0[e]);
                    vbf[4 + e] = (short)f2bf(v1[e]);
                }
                #pragma unroll
                for (int qt = 0; qt < 2; ++qt)
                    acc[qt][dt] = __builtin_amdgcn_mfma_f32_16x16x32_bf16(pfrag[qt][s], vbf, acc[qt][dt], 0, 0, 0);
            }
    }

    __shared__ float obuf[32][DD + 4];
    __shared__ float mbuf[8][32];
    __shared__ float lbuf[8][32];
    __shared__ float lsbuf[32];
    #pragma unroll
    for (int qt = 0; qt < 2; ++qt) {
        lrun[qt] += __shfl_xor(lrun[qt], 16, 64);
        lrun[qt] += __shfl_xor(lrun[qt], 32, 64);
    }
    if (lane < 16) {
        mbuf[wave][c]      = mrun[0];
        mbuf[wave][16 + c] = mrun[1];
        lbuf[wave][c]      = lrun[0];
        lbuf[wave][16 + c] = lrun[1];
    }
    for (int i = tid; i < 32 * (DD + 4); i += 512)
        (&obuf[0][0])[i] = 0.f;
    __syncthreads();
    float fac[2];
    {
        float lst[2];
        #pragma unroll
        for (int qt = 0; qt < 2; ++qt) {
            int q = qt * 16 + c;
            float mm = -INFINITY;
            #pragma unroll
            for (int w = 0; w < 8; ++w) mm = fmaxf(mm, mbuf[w][q]);
            float ls = 0.f;
            #pragma unroll
            for (int w = 0; w < 8; ++w)
                ls += __builtin_amdgcn_exp2f(mbuf[w][q] - mm) * lbuf[w][q];
            fac[qt] = __builtin_amdgcn_exp2f(mrun[qt] - mm);
            lst[qt] = ls;
        }
        if (wave == 0 && lane < 16) {
            lsbuf[c]      = lst[0];
            lsbuf[16 + c] = lst[1];
        }
    }
    float facr[2][4];
    #pragma unroll
    for (int qt = 0; qt < 2; ++qt)
        #pragma unroll
        for (int r = 0; r < 4; ++r)
            facr[qt][r] = __shfl(fac[qt], 4 * g + r, 64);
    for (int w = 0; w < 8; ++w) {
        if (wave == w) {
            #pragma unroll
            for (int qt = 0; qt < 2; ++qt)
                #pragma unroll
                for (int dt = 0; dt < 8; ++dt)
                    #pragma unroll
                    for (int r = 0; r < 4; ++r)
                        obuf[qt * 16 + 4 * g + r][dt * 16 + c] += facr[qt][r] * acc[qt][dt][r];
        }
        __syncthreads();
    }
    const int qq = tid & 31;
    const int dg = tid >> 5;
    const float inv = 1.f / lsbuf[qq];
    #pragma unroll
    for (int i = 0; i < 8; ++i) {
        int d = dg * 8 + i;
        out[(size_t)d * NN + q0 + qq] = obuf[qq][d] * inv;
    }
}

extern "C" void kernel_launch(void* const* d_in, const int* in_sizes, int n_in,
                              void* d_out, int out_size, void* d_ws, size_t ws_size,
                              hipStream_t stream) {
    const float* Q = (const float*)d_in[0];
    const float* K = (const float*)d_in[1];
    const float* V = (const float*)d_in[2];
    float* out = (float*)d_out;

    if (ws_size < WS_NEED || d_ws == nullptr) {
        hipLaunchKernelGGL(attn_fwd_fb, dim3(NN / 32), dim3(512), 0, stream, Q, K, V, out);
        return;
    }
    char* ws = (char*)d_ws;
    char* kst = ws;
    float* mArr = (float*)(ws + WS_M);
    float* lArr = (float*)(ws + WS_L);
    _Float16* opart = (_Float16*)(ws + WS_OP);

    hipLaunchKernelGGL(attn_prep, dim3(NTILES), dim3(256), 0, stream, K, V, kst);
    hipLaunchKernelGGL(attn_main, dim3(KSPLIT * (NN / BQ)), dim3(256), 0, stream, Q, kst, mArr, lArr, opart);
    hipLaunchKernelGGL(attn_combine, dim3((NN / 512) * 8), dim3(256), 0, stream, opart, mArr, lArr, out);
}

// Round 12
// 69.008 us; speedup vs baseline: 1.7661x; 1.0878x over previous
//
#include <hip/hip_runtime.h>

#define NN 8192
#define DD 128
#define KSPLIT 16
#define KCHUNK (NN / KSPLIT)      // 512 k per WG
#define BK 32
#define NT (KCHUNK / BK)          // 16 tiles per WG
#define NTILES (NN / BK)          // 256 tiles total
#define TILE_B 16384              // K fp16 8K | Vp fp16 8K
#define OFF_V 8192
#define WAVES 4
#define BQ (WAVES * 32)           // 128 q per WG

// ws layout
#define WS_M   ((size_t)NTILES * TILE_B)                 // 4 MB kst
#define WS_L   (WS_M + (size_t)KSPLIT * NN * 4)
#define WS_OP  (WS_L + (size_t)KSPLIT * NN * 4)
#define WS_NEED (WS_OP + (size_t)KSPLIT * NN * DD * 2)   // ~38.8 MB

typedef __attribute__((ext_vector_type(8))) _Float16 f16x8;
typedef __attribute__((ext_vector_type(2))) _Float16 f16x2;
typedef __attribute__((ext_vector_type(2))) __fp16 fp16v2;
typedef __attribute__((ext_vector_type(8))) short bf16x8;
typedef __attribute__((ext_vector_type(4))) float f32x4;
typedef __attribute__((ext_vector_type(2))) float f32x2;
typedef __attribute__((ext_vector_type(16))) float f32x16;

static __device__ __forceinline__ unsigned short f2bf(float f) {
    union { float f; unsigned u; } v; v.f = f;
    return (unsigned short)((v.u + 0x7FFFu + ((v.u >> 16) & 1u)) >> 16);
}
static __device__ __forceinline__ float bf2f(unsigned short h) {
    union { unsigned u; float f; } v; v.u = ((unsigned)h) << 16;
    return v.f;
}
static __device__ __forceinline__ void gld_lds16(const char* g, char* l) {
    __builtin_amdgcn_global_load_lds(
        (const __attribute__((address_space(1))) unsigned*)g,
        (__attribute__((address_space(3))) unsigned*)l,
        16, 0, 0);
}

// ---------------- prep: build swizzled fp16 tile images ----------------
__global__ __launch_bounds__(256) void attn_prep(
    const float* __restrict__ Km, const float* __restrict__ Vm,
    char* __restrict__ kst)
{
    __shared__ __align__(16) char img[TILE_B];
    const int tt = blockIdx.x;
    const int tid = threadIdx.x;
    const int k0 = tt * BK;
    // K: logical [k][d] fp16, row 256B, swizzle ^((k&15)<<4)  (16-slot XOR)
    #pragma unroll
    for (int i = 0; i < 16; ++i) {
        int idx = i * 256 + tid;
        int d = idx >> 5, k = idx & 31;
        float kv = Km[(size_t)d * NN + k0 + k];
        int b = (k * 256 + d * 2) ^ ((k & 15) << 4);
        *(_Float16*)(img + b) = (_Float16)kv;
    }
    // V: logical [d][j] fp16, row 64B, swizzle ^((d&15)<<4)  (16-slot XOR)
    // j = s2*16 + h*8 + jj  maps actual k = (jj&3) + 4h + 8*(jj>>2) + 16*s2
    #pragma unroll
    for (int i = 0; i < 16; ++i) {
        int idx = i * 256 + tid;
        int d = idx >> 5, j = idx & 31;
        int kl = (j & 3) + 4 * ((j >> 3) & 1) + 8 * ((j >> 2) & 1) + 16 * (j >> 4);
        float vv = Vm[(size_t)d * NN + k0 + kl];
        int b = (d * 64 + j * 2) ^ ((d & 15) << 4);
        *(_Float16*)(img + OFF_V + b) = (_Float16)vv;
    }
    __syncthreads();
    float4* dst = (float4*)(kst + (size_t)tt * TILE_B);
    const float4* src = (const float4*)img;
    #pragma unroll
    for (int i = 0; i < 4; ++i) dst[i * 256 + tid] = src[i * 256 + tid];
}

// ---------------- main: flash attention, fp16 32x32 MFMA, T4 schedule ----------------
__global__ __launch_bounds__(256, 3) void attn_main(
    const float* __restrict__ Qm, const char* __restrict__ kst,
    float* __restrict__ mArr, float* __restrict__ lArr,
    _Float16* __restrict__ opart)
{
    __shared__ __align__(16) char smem[3 * TILE_B];   // 48KB, 3-deep ring
    const int tid = threadIdx.x;
    const int wave = tid >> 6, lane = tid & 63;
    const int q31 = lane & 31;
    const int h = lane >> 5;
    const int swz = (q31 & 15) << 4;   // shared by K and V reads
    const int ks = blockIdx.x & (KSPLIT - 1);
    const int qb = blockIdx.x >> 4;
    const int q0w = qb * BQ + wave * 32;
    const int qg = q0w + q31;
    const float LOG2E = 1.44269504088896340736f;

    // Q fragments: elem jj of qh[ds] = fp16(Q[16ds+8h+jj][qg]*log2e)
    f16x8 qh[8];
    #pragma unroll
    for (int ds = 0; ds < 8; ++ds)
        #pragma unroll
        for (int jj = 0; jj < 8; ++jj) {
            int d = 16 * ds + 8 * h + jj;
            qh[ds][jj] = (_Float16)(Qm[(size_t)d * NN + qg] * LOG2E);
        }

    f32x16 acc[4];
    #pragma unroll
    for (int dt = 0; dt < 4; ++dt)
        #pragma unroll
        for (int r = 0; r < 16; ++r) acc[dt][r] = 0.f;
    // mrun init 40: p = exp2(T-40) <= 2^8 after defer-check; fp16-safe, fp32-safe.
    float mrun = 40.f, lrun = 0.f;

    const int rot = qb & (NT - 1);   // decorrelate WGs sharing this kst slice
    const char* kwg = kst + (size_t)(ks * NT) * TILE_B + tid * 16;

#define STAGE(T_, BI_)                                                      \
    {                                                                       \
        int tp_ = ((T_) + rot) & (NT - 1);                                  \
        const char* gs_ = kwg + (size_t)tp_ * TILE_B;                       \
        char* ld_ = smem + (BI_) * TILE_B + tid * 16;                       \
        gld_lds16(gs_,         ld_);                                        \
        gld_lds16(gs_ + 4096,  ld_ + 4096);                                 \
        gld_lds16(gs_ + 8192,  ld_ + 8192);                                 \
        gld_lds16(gs_ + 12288, ld_ + 12288);                                \
    }

    // prologue: stage tiles 0,1 (8 loads/thread outstanding)
    STAGE(0, 0);
    STAGE(1, 1);

    int bcur = 0;
    for (int t = 0; t < NT; ++t) {
        // counted wait: allow next tile's 4 loads to stay in flight (T4);
        // oldest 4 (this tile's) must have landed.
        asm volatile("s_waitcnt vmcnt(4)" ::: "memory");
        __builtin_amdgcn_sched_barrier(0);
        __builtin_amdgcn_s_barrier();
        __builtin_amdgcn_sched_barrier(0);

        const char* kb = smem + bcur * TILE_B;

        if (t + 2 < NT) {   // prefetch 2 ahead into the free ring slot
            int bn = bcur + 2; if (bn >= 3) bn -= 3;
            STAGE(t + 2, bn);
        }

        // ---- QK^T: S^T[k=32][q=32], single fp16 chain, 8 d-steps of 16
        f32x16 T;
        #pragma unroll
        for (int r = 0; r < 16; ++r) T[r] = 0.f;
        __builtin_amdgcn_s_setprio(1);
        #pragma unroll
        for (int ds = 0; ds < 8; ++ds) {
            int off = ((q31 << 8) + ds * 32 + (h << 4)) ^ swz;
            f16x8 kh = *(const f16x8*)(kb + off);
            T = __builtin_amdgcn_mfma_f32_32x32x16_f16(kh, qh[ds], T, 0, 0, 0);
        }
        __builtin_amdgcn_s_setprio(0);

        // ---- speculative softmax: exps start immediately off mrun_old
        float p[16];
        #pragma unroll
        for (int r = 0; r < 16; ++r)
            p[r] = __builtin_amdgcn_exp2f(T[r] - mrun);

        float a0 = fmaxf(fmaxf(T[0], T[1]), T[2]);
        float a1 = fmaxf(fmaxf(T[3], T[4]), T[5]);
        float a2 = fmaxf(fmaxf(T[6], T[7]), T[8]);
        float a3 = fmaxf(fmaxf(T[9], T[10]), T[11]);
        float a4 = fmaxf(fmaxf(T[12], T[13]), T[14]);
        float tmax = fmaxf(fmaxf(fmaxf(a0, a1), a2), fmaxf(fmaxf(a3, a4), T[15]));
        tmax = fmaxf(tmax, __shfl_xor(tmax, 32, 64));

        if (__any(tmax > mrun + 8.f)) {   // rare: joint rescale keeps p bounded by 2^8
            float mnew = fmaxf(mrun, tmax);
            float sc = __builtin_amdgcn_exp2f(mrun - mnew);
            mrun = mnew; lrun *= sc;
            #pragma unroll
            for (int r = 0; r < 16; ++r) p[r] *= sc;
            #pragma unroll
            for (int dt = 0; dt < 4; ++dt)
                #pragma unroll
                for (int r = 0; r < 16; ++r) acc[dt][r] *= sc;
        }

        float s0 = (p[0] + p[1]) + (p[2] + p[3]);
        float s1 = (p[4] + p[5]) + (p[6] + p[7]);
        float s2 = (p[8] + p[9]) + (p[10] + p[11]);
        float s3 = (p[12] + p[13]) + (p[14] + p[15]);
        lrun += (s0 + s1) + (s2 + s3);
        union { f16x8 v[2]; fp16v2 h2[8]; } pu;
        #pragma unroll
        for (int r = 0; r < 8; ++r)
            pu.h2[r] = __builtin_amdgcn_cvt_pkrtz(p[2 * r], p[2 * r + 1]);

        // ---- PV: O^T[d][q] += V^T * P  (k-permuted contraction)
        const char* vb = kb + OFF_V;
        __builtin_amdgcn_s_setprio(1);
        #pragma unroll
        for (int dt = 0; dt < 4; ++dt) {
            int vbase = (dt * 32 + q31) * 64 + (h << 4);
            f16x8 v0 = *(const f16x8*)(vb + ((vbase) ^ swz));
            f16x8 v1 = *(const f16x8*)(vb + ((vbase + 32) ^ swz));
            acc[dt] = __builtin_amdgcn_mfma_f32_32x32x16_f16(v0, pu.v[0], acc[dt], 0, 0, 0);
            acc[dt] = __builtin_amdgcn_mfma_f32_32x32x16_f16(v1, pu.v[1], acc[dt], 0, 0, 0);
        }
        __builtin_amdgcn_s_setprio(0);

        bcur = (bcur + 1 == 3) ? 0 : bcur + 1;
    }
#undef STAGE

    // ---- epilogue: partials to ws (non-temporal: write-once)
    lrun += __shfl_xor(lrun, 32, 64);
    if (lane < 32) {
        __builtin_nontemporal_store(mrun, &mArr[ks * NN + qg]);
        __builtin_nontemporal_store(lrun, &lArr[ks * NN + qg]);
    }
    #pragma unroll
    for (int dt = 0; dt < 4; ++dt)
        #pragma unroll
        for (int r = 0; r < 16; ++r) {
            int d = dt * 32 + (r & 3) + 8 * (r >> 2) + 4 * h;
            __builtin_nontemporal_store((_Float16)acc[dt][r],
                &opart[((size_t)ks * DD + d) * NN + qg]);
        }
}

// ---------------- combine: merge split-k partials (256 WGs) ----------------
__global__ __launch_bounds__(256) void attn_combine(
    const _Float16* __restrict__ opart, const float* __restrict__ mArr,
    const float* __restrict__ lArr, float* __restrict__ out)
{
    const int tid = threadIdx.x;
    const int qg = blockIdx.x >> 4;            // 16 q-groups of 512
    const int dseg = (blockIdx.x & 15) * 8;    // 16 d-segments of 8
    const int q = qg * 512 + tid * 2;

    f32x2 mv[KSPLIT];
    float M0 = -INFINITY, M1 = -INFINITY;
    #pragma unroll
    for (int s = 0; s < KSPLIT; ++s) {
        mv[s] = *(const f32x2*)&mArr[(size_t)s * NN + q];
        M0 = fmaxf(M0, mv[s][0]);
        M1 = fmaxf(M1, mv[s][1]);
    }
    float L0 = 0.f, L1 = 0.f;
    f32x2 w[KSPLIT];
    #pragma unroll
    for (int s = 0; s < KSPLIT; ++s) {
        f32x2 lv = *(const f32x2*)&lArr[(size_t)s * NN + q];
        w[s][0] = __builtin_amdgcn_exp2f(mv[s][0] - M0);
        w[s][1] = __builtin_amdgcn_exp2f(mv[s][1] - M1);
        L0 += w[s][0] * lv[0];
        L1 += w[s][1] * lv[1];
    }
    float i0 = 1.f / L0, i1 = 1.f / L1;
    #pragma unroll
    for (int s = 0; s < KSPLIT; ++s) { w[s][0] *= i0; w[s][1] *= i1; }

    for (int dd = 0; dd < 8; ++dd) {
        int d = dseg + dd;
        float a0 = 0.f, a1 = 0.f;
        #pragma unroll
        for (int s = 0; s < KSPLIT; ++s) {
            f16x2 u = __builtin_nontemporal_load(
                (const f16x2*)&opart[((size_t)s * DD + d) * NN + q]);
            a0 += w[s][0] * (float)u[0];
            a1 += w[s][1] * (float)u[1];
        }
        f32x2 o; o[0] = a0; o[1] = a1;
        *(f32x2*)&out[(size_t)d * NN + q] = o;
    }
}

// ---------------- fallback (round-1 kernel, used if ws too small) ----------------
__global__ __launch_bounds__(512, 2) void attn_fwd_fb(
    const float* __restrict__ Qm, const float* __restrict__ Km,
    const float* __restrict__ Vm, float* __restrict__ out)
{
    const int tid  = threadIdx.x;
    const int wave = tid >> 6;
    const int lane = tid & 63;
    const int c = lane & 15;
    const int g = lane >> 4;
    const int q0 = blockIdx.x * 32;
    const float LOG2E = 1.44269504088896340736f;

    bf16x8 qhi[2][4], qlo[2][4];
    #pragma unroll
    for (int qt = 0; qt < 2; ++qt)
        #pragma unroll
        for (int ds = 0; ds < 4; ++ds)
            #pragma unroll
            for (int jj = 0; jj < 8; ++jj) {
                int d = ds * 32 + 8 * g + jj;
                float qv = Qm[(size_t)d * NN + (q0 + qt * 16 + c)] * LOG2E;
                unsigned short hv = f2bf(qv);
                qhi[qt][ds][jj] = (short)hv;
                qlo[qt][ds][jj] = (short)f2bf(qv - bf2f(hv));
            }

    f32x4 acc[2][8];
    #pragma unroll
    for (int a = 0; a < 2; ++a)
        #pragma unroll
        for (int b = 0; b < 8; ++b)
            acc[a][b] = (f32x4){0.f, 0.f, 0.f, 0.f};
    float mrun[2] = {-INFINITY, -INFINITY};
    float lrun[2] = {0.f, 0.f};
    const int kw0 = wave * (NN / 8);

    for (int t = 0; t < (NN / 8) / 64; ++t) {
        const int k0 = kw0 + t * 64;
        f32x4 T[4][2];
        #pragma unroll
        for (int mkt = 0; mkt < 4; ++mkt) {
            T[mkt][0] = (f32x4){0.f, 0.f, 0.f, 0.f};
            T[mkt][1] = (f32x4){0.f, 0.f, 0.f, 0.f};
        }
        #pragma unroll
        for (int mkt = 0; mkt < 4; ++mkt) {
            const int kc = k0 + mkt * 16 + c;
            #pragma unroll
            for (int ds = 0; ds < 4; ++ds) {
                bf16x8 khi, klo;
                #pragma unroll
                for (int jj = 0; jj < 8; ++jj) {
                    int d = ds * 32 + 8 * g + jj;
                    float kv = Km[(size_t)d * NN + kc];
                    unsigned short hv = f2bf(kv);
                    khi[jj] = (short)hv;
                    klo[jj] = (short)f2bf(kv - bf2f(hv));
                }
                #pragma unroll
                for (int qt = 0; qt < 2; ++qt) {
                    T[mkt][qt] = __builtin_amdgcn_mfma_f32_16x16x32_bf16(khi, qhi[qt][ds], T[mkt][qt], 0, 0, 0);
                    T[mkt][qt] = __builtin_amdgcn_mfma_f32_16x16x32_bf16(khi, qlo[qt][ds], T[mkt][qt], 0, 0, 0);
                    T[mkt][qt] = __builtin_amdgcn_mfma_f32_16x16x32_bf16(klo, qhi[qt][ds], T[mkt][qt], 0, 0, 0);
                }
            }
        }
        bf16x8 pfrag[2][2];
        float scl[2];
        #pragma unroll
        for (int qt = 0; qt < 2; ++qt) {
            float tmax = T[0][qt][0];
            #pragma unroll
            for (int mkt = 0; mkt < 4; ++mkt)
                #pragma unroll
                for (int r = 0; r < 4; ++r)
                    tmax = fmaxf(tmax, T[mkt][qt][r]);
            tmax = fmaxf(tmax, __shfl_xor(tmax, 16, 64));
            tmax = fmaxf(tmax, __shfl_xor(tmax, 32, 64));
            float mnew = fmaxf(mrun[qt], tmax);
            float sc = __builtin_amdgcn_exp2f(mrun[qt] - mnew);
            mrun[qt] = mnew;
            lrun[qt] *= sc;
            scl[qt] = sc;
            #pragma unroll
            for (int s = 0; s < 2; ++s)
                #pragma unroll
                for (int hf = 0; hf < 2; ++hf) {
                    int mkt = 2 * s + hf;
                    #pragma unroll
                    for (int r = 0; r < 4; ++r) {
                        float pv = __builtin_amdgcn_exp2f(T[mkt][qt][r] - mnew);
                        unsigned short pb = f2bf(pv);
                        lrun[qt] += bf2f(pb);
                        pfrag[qt][s][hf * 4 + r] = (short)pb;
                    }
                }
        }
        #pragma unroll
        for (int qt = 0; qt < 2; ++qt)
            #pragma unroll
            for (int r = 0; r < 4; ++r) {
                float f = __shfl(scl[qt], 4 * g + r, 64);
                #pragma unroll
                for (int dt = 0; dt < 8; ++dt)
                    acc[qt][dt][r] *= f;
            }
        #pragma unroll
        for (int s = 0; s < 2; ++s)
            #pragma unroll
            for (int dt = 0; dt < 8; ++dt) {
                const float* vp = Vm + (size_t)(dt * 16 + c) * NN + (k0 + 32 * s + 4 * g);
                f32x4 v0 = *(const f32x4*)vp;
                f32x4 v1 = *(const f32x4*)(vp + 16);
                bf16x8 vbf;
                #pragma unroll
                for (int e = 0; e < 4; ++e) {
                    vbf[e]     = (short)f2bf(v0[e]);
                    vbf[4 + e] = (short)f2bf(v1[e]);
                }
                #pragma unroll
                for (int qt = 0; qt < 2; ++qt)
                    acc[qt][dt] = __builtin_amdgcn_mfma_f32_16x16x32_bf16(pfrag[qt][s], vbf, acc[qt][dt], 0, 0, 0);
            }
    }

    __shared__ float obuf[32][DD + 4];
    __shared__ float mbuf[8][32];
    __shared__ float lbuf[8][32];
    __shared__ float lsbuf[32];
    #pragma unroll
    for (int qt = 0; qt < 2; ++qt) {
        lrun[qt] += __shfl_xor(lrun[qt], 16, 64);
        lrun[qt] += __shfl_xor(lrun[qt], 32, 64);
    }
    if (lane < 16) {
        mbuf[wave][c]      = mrun[0];
        mbuf[wave][16 + c] = mrun[1];
        lbuf[wave][c]      = lrun[0];
        lbuf[wave][16 + c] = lrun[1];
    }
    for (int i = tid; i < 32 * (DD + 4); i += 512)
        (&obuf[0][0])[i] = 0.f;
    __syncthreads();
    float fac[2];
    {
        float lst[2];
        #pragma unroll
        for (int qt = 0; qt < 2; ++qt) {
            int q = qt * 16 + c;
            float mm = -INFINITY;
            #pragma unroll
            for (int w = 0; w < 8; ++w) mm = fmaxf(mm, mbuf[w][q]);
            float ls = 0.f;
            #pragma unroll
            for (int w = 0; w < 8; ++w)
                ls += __builtin_amdgcn_exp2f(mbuf[w][q] - mm) * lbuf[w][q];
            fac[qt] = __builtin_amdgcn_exp2f(mrun[qt] - mm);
            lst[qt] = ls;
        }
        if (wave == 0 && lane < 16) {
            lsbuf[c]      = lst[0];
            lsbuf[16 + c] = lst[1];
        }
    }
    float facr[2][4];
    #pragma unroll
    for (int qt = 0; qt < 2; ++qt)
        #pragma unroll
        for (int r = 0; r < 4; ++r)
            facr[qt][r] = __shfl(fac[qt], 4 * g + r, 64);
    for (int w = 0; w < 8; ++w) {
        if (wave == w) {
            #pragma unroll
            for (int qt = 0; qt < 2; ++qt)
                #pragma unroll
                for (int dt = 0; dt < 8; ++dt)
                    #pragma unroll
                    for (int r = 0; r < 4; ++r)
                        obuf[qt * 16 + 4 * g + r][dt * 16 + c] += facr[qt][r] * acc[qt][dt][r];
        }
        __syncthreads();
    }
    const int qq = tid & 31;
    const int dg = tid >> 5;
    const float inv = 1.f / lsbuf[qq];
    #pragma unroll
    for (int i = 0; i < 8; ++i) {
        int d = dg * 8 + i;
        out[(size_t)d * NN + q0 + qq] = obuf[qq][d] * inv;
    }
}

extern "C" void kernel_launch(void* const* d_in, const int* in_sizes, int n_in,
                              void* d_out, int out_size, void* d_ws, size_t ws_size,
                              hipStream_t stream) {
    const float* Q = (const float*)d_in[0];
    const float* K = (const float*)d_in[1];
    const float* V = (const float*)d_in[2];
    float* out = (float*)d_out;

    if (ws_size < WS_NEED || d_ws == nullptr) {
        hipLaunchKernelGGL(attn_fwd_fb, dim3(NN / 32), dim3(512), 0, stream, Q, K, V, out);
        return;
    }
    char* ws = (char*)d_ws;
    char* kst = ws;
    float* mArr = (float*)(ws + WS_M);
    float* lArr = (float*)(ws + WS_L);
    _Float16* opart = (_Float16*)(ws + WS_OP);

    hipLaunchKernelGGL(attn_prep, dim3(NTILES), dim3(256), 0, stream, K, V, kst);
    hipLaunchKernelGGL(attn_main, dim3(KSPLIT * (NN / BQ)), dim3(256), 0, stream, Q, kst, mArr, lArr, opart);
    hipLaunchKernelGGL(attn_combine, dim3((NN / 512) * 16), dim3(256), 0, stream, opart, mArr, lArr, out);
}